// Round 1
// baseline (372.984 us; speedup 1.0000x reference)
//
#include <hip/hip_runtime.h>
#include <math.h>

// ---------------- workspace layout (bytes) ----------------
// [0..40)   : 10 float max slots: 0 x, 1 w1, 2 w2, 3 w3, 4 fw1, 5 fw2,
//             6 a1max, 7 a2max, 8 a3max, 9 a4max
#define O_QX    (1024)      // 25088 B  quantized x (32,1,28,28)
#define O_QW1   (32768)     // 400 B
#define O_QW2   (65536)     // 12800 B
#define O_QW3   (131072)    // 51200 B
#define O_QFW1  (262144)    // 262144 B
#define O_QFW2  (524288)    // 2560 B
#define O_A1    (589824)    // 100352 floats (32,16,14,14)
#define O_A2    (1048576)   // 50176 floats  (32,32,7,7)
#define O_A3    (1310720)   // 32768 floats  (32,1024)
#define O_A4    (1572864)   // 8192 floats   (32,256)

__device__ __forceinline__ float blk_max(float v, float* red) {
  int t = threadIdx.x;
  red[t] = v;
  __syncthreads();
  for (int s = (int)blockDim.x >> 1; s > 0; s >>= 1) {
    if (t < s) red[t] = fmaxf(red[t], red[t + s]);
    __syncthreads();
  }
  return red[0];
}

__device__ __forceinline__ unsigned char quant1(float v, float s) {
  float q = rintf(v * s);
  q = fminf(fmaxf(q, 0.0f), 255.0f);
  return (unsigned char)q;
}

// ---- kernel 1: per-tensor abs-max of the 6 static tensors; zero activation slots
__global__ __launch_bounds__(256) void k_maxes(const float* x, const float* w1, const float* w2,
                                               const float* w3, const float* fw1, const float* fw2,
                                               float* wsf) {
  __shared__ float red[256];
  const float* p; int n;
  switch (blockIdx.x) {
    case 0: p = x;   n = 25088;  break;
    case 1: p = w1;  n = 400;    break;
    case 2: p = w2;  n = 12800;  break;
    case 3: p = w3;  n = 51200;  break;
    case 4: p = fw1; n = 262144; break;
    default: p = fw2; n = 2560;  break;
  }
  float m = 0.f;
  for (int i = threadIdx.x; i < n; i += 256) m = fmaxf(m, fabsf(p[i]));
  m = blk_max(m, red);
  if (threadIdx.x == 0) wsf[blockIdx.x] = m;
  if (blockIdx.x == 0 && threadIdx.x >= 6 && threadIdx.x < 10) wsf[threadIdx.x] = 0.f;
}

// ---- kernel 2: quantize x + all weights to uint8 in ws
__global__ __launch_bounds__(256) void k_quant(const float* x, const float* w1, const float* w2,
                                               const float* w3, const float* fw1, const float* fw2,
                                               unsigned char* ws8, const float* wsf) {
  const float* p; int n; unsigned char* d;
  switch (blockIdx.y) {
    case 0: p = x;   n = 25088;  d = ws8 + O_QX;   break;
    case 1: p = w1;  n = 400;    d = ws8 + O_QW1;  break;
    case 2: p = w2;  n = 12800;  d = ws8 + O_QW2;  break;
    case 3: p = w3;  n = 51200;  d = ws8 + O_QW3;  break;
    case 4: p = fw1; n = 262144; d = ws8 + O_QFW1; break;
    default: p = fw2; n = 2560;  d = ws8 + O_QFW2; break;
  }
  int i = blockIdx.x * 256 + threadIdx.x;
  if (i >= n) return;
  float s = 255.0f / fmaxf(wsf[blockIdx.y], 1e-6f);
  d[i] = quant1(p[i], s);
}

// ---- kernel 3: conv1 (1->16, 5x5 pad2) + relu + 2x2 maxpool -> A1 (32,16,14,14) + max slot 6
__global__ __launch_bounds__(256) void k_conv1(const unsigned char* ws8, const float* b1,
                                               float* a1, float* wsf) {
  int b = blockIdx.x, og = blockIdx.y;              // 4 out-channels per og (4 groups)
  __shared__ unsigned char sx[32 * 32];             // 28+4 padded
  __shared__ short sw[4 * 25];
  __shared__ float red[256];
  const unsigned char* qx = ws8 + O_QX + b * 784;
  const unsigned char* qw = ws8 + O_QW1 + og * 4 * 25;
  for (int i = threadIdx.x; i < 1024; i += 256) sx[i] = 0;
  __syncthreads();
  for (int i = threadIdx.x; i < 784; i += 256) {
    int y = i / 28, xx = i - y * 28;
    sx[(y + 2) * 32 + xx + 2] = qx[i];
  }
  for (int i = threadIdx.x; i < 100; i += 256) sw[i] = qw[i];
  __syncthreads();
  float lm = 0.f;
  for (int oi = threadIdx.x; oi < 784; oi += 256) {  // 4 oc * 196 pool px
    int ol = oi / 196, r = oi - ol * 196;
    int py = r / 14, px = r - py * 14;
    int o = og * 4 + ol;
    const short* w = sw + ol * 25;
    int best = -2147483647;
#pragma unroll
    for (int dy = 0; dy < 2; ++dy)
#pragma unroll
      for (int dx = 0; dx < 2; ++dx) {
        int cy = 2 * py + dy, cx = 2 * px + dx;
        int acc = 0;
#pragma unroll
        for (int kh = 0; kh < 5; ++kh) {
          const unsigned char* xp = sx + (cy + kh) * 32 + cx;
#pragma unroll
          for (int kw = 0; kw < 5; ++kw)
            acc += ((int)xp[kw] * (int)w[kh * 5 + kw]) >> 8;
        }
        best = max(best, acc);
      }
    float v = fmaxf(0.f, (float)best + b1[o]);
    a1[b * 3136 + o * 196 + r] = v;
    lm = fmaxf(lm, v);
  }
  lm = blk_max(lm, red);
  if (threadIdx.x == 0) atomicMax((unsigned int*)(wsf + 6), __float_as_uint(lm));
}

// ---- kernel 4: conv2 (16->32) + relu + pool -> A2 (32,32,7,7) + max slot 7
__global__ __launch_bounds__(256) void k_conv2(const unsigned char* ws8, const float* a1,
                                               const float* b2, float* a2, float* wsf) {
  int b = blockIdx.x, og = blockIdx.y;              // 4 oc per og (8 groups)
  __shared__ unsigned char sa[16 * 18 * 18];        // 14+4 padded per channel
  __shared__ short sw[4 * 400];
  __shared__ float red[256];
  float s1 = 255.0f / fmaxf(wsf[6], 1e-6f);
  for (int i = threadIdx.x; i < 16 * 324; i += 256) sa[i] = 0;
  __syncthreads();
  for (int i = threadIdx.x; i < 3136; i += 256) {
    int c = i / 196, r = i - c * 196;
    int y = r / 14, xx = r - y * 14;
    sa[c * 324 + (y + 2) * 18 + xx + 2] = quant1(a1[b * 3136 + i], s1);
  }
  const unsigned char* qw = ws8 + O_QW2 + og * 4 * 400;
  for (int i = threadIdx.x; i < 1600; i += 256) sw[i] = qw[i];
  __syncthreads();
  float lm = 0.f;
  int oi = threadIdx.x;
  if (oi < 196) {                                    // 4 oc * 49 pool px
    int ol = oi / 49, r = oi - ol * 49;
    int py = r / 7, px = r - py * 7;
    int o = og * 4 + ol;
    int best = -2147483647;
#pragma unroll
    for (int dy = 0; dy < 2; ++dy)
#pragma unroll
      for (int dx = 0; dx < 2; ++dx) {
        int cy = 2 * py + dy, cx = 2 * px + dx;      // 0..13
        int acc = 0;
        for (int c = 0; c < 16; ++c) {
          const unsigned char* ap = sa + c * 324 + cy * 18 + cx;
          const short* wp = sw + ol * 400 + c * 25;
#pragma unroll
          for (int kh = 0; kh < 5; ++kh)
#pragma unroll
            for (int kw = 0; kw < 5; ++kw)
              acc += ((int)ap[kh * 18 + kw] * (int)wp[kh * 5 + kw]) >> 8;
        }
        best = max(best, acc);
      }
    float v = fmaxf(0.f, (float)best + b2[o]);
    a2[b * 1568 + o * 49 + r] = v;
    lm = v;
  }
  lm = blk_max(lm, red);
  if (threadIdx.x == 0) atomicMax((unsigned int*)(wsf + 7), __float_as_uint(lm));
}

// ---- kernel 5: conv3 (32->64) + relu + pool(pad=1) -> A3 (32,1024) + max slot 8
__global__ __launch_bounds__(256) void k_conv3(const unsigned char* ws8, const float* a2,
                                               const float* b3, float* a3, float* wsf) {
  int b = blockIdx.x, og = blockIdx.y;              // 8 oc per og (8 groups)
  __shared__ unsigned char sa[32 * 11 * 11];        // 7+4 padded
  __shared__ short sw[8 * 800];
  __shared__ int part[256 * 4];
  __shared__ float red[256];
  float s2 = 255.0f / fmaxf(wsf[7], 1e-6f);
  for (int i = threadIdx.x; i < 32 * 121; i += 256) sa[i] = 0;
  __syncthreads();
  for (int i = threadIdx.x; i < 1568; i += 256) {
    int c = i / 49, r = i - c * 49;
    int y = r / 7, xx = r - y * 7;
    sa[c * 121 + (y + 2) * 11 + xx + 2] = quant1(a2[b * 1568 + i], s2);
  }
  const unsigned char* qw = ws8 + O_QW3 + og * 8 * 800;
  for (int i = threadIdx.x; i < 6400; i += 256) sw[i] = qw[i];
  __syncthreads();
  // 128 outputs (8 oc * 16 pool px), 2-way channel split
  int out  = threadIdx.x & 127;
  int half = threadIdx.x >> 7;
  int ol = out >> 4, r = out & 15;
  int py = r >> 2, px = r & 3;
#pragma unroll
  for (int dy = 0; dy < 2; ++dy)
#pragma unroll
    for (int dx = 0; dx < 2; ++dx) {
      int idx = dy * 2 + dx;
      int cy = 2 * py - 1 + dy, cx = 2 * px - 1 + dx;  // pool pad=1
      int acc;
      if (cy < 0 || cy > 6 || cx < 0 || cx > 6) {
        acc = -(1 << 28);
      } else {
        acc = 0;
        for (int ci = 0; ci < 16; ++ci) {
          int c = half * 16 + ci;
          const unsigned char* ap = sa + c * 121 + cy * 11 + cx;
          const short* wp = sw + ol * 800 + c * 25;
#pragma unroll
          for (int kh = 0; kh < 5; ++kh)
#pragma unroll
            for (int kw = 0; kw < 5; ++kw)
              acc += ((int)ap[kh * 11 + kw] * (int)wp[kh * 5 + kw]) >> 8;
        }
      }
      part[threadIdx.x * 4 + idx] = acc;
    }
  __syncthreads();
  float lm = 0.f;
  if (half == 0) {
    int best = -2147483647;
#pragma unroll
    for (int idx = 0; idx < 4; ++idx) {
      int acc = part[threadIdx.x * 4 + idx] + part[(threadIdx.x + 128) * 4 + idx];
      best = max(best, acc);
    }
    int o = og * 8 + ol;
    float v = fmaxf(0.f, (float)best + b3[o]);
    a3[b * 1024 + o * 16 + r] = v;   // flatten order (c, y, x)
    lm = v;
  }
  lm = blk_max(lm, red);
  if (threadIdx.x == 0) atomicMax((unsigned int*)(wsf + 8), __float_as_uint(lm));
}

// ---- kernel 6: dense1 (1024 -> 256) + relu -> A4 (32,256) + max slot 9
__global__ __launch_bounds__(256) void k_dense1(const unsigned char* ws8, const float* a3f,
                                                const float* fb1, float* a4, float* wsf) {
  int b = blockIdx.x, og = blockIdx.y;              // 32 oc per og (8 groups)
  __shared__ unsigned char sh[1024];
  __shared__ float red[256];
  float s3 = 255.0f / fmaxf(wsf[8], 1e-6f);
  for (int i = threadIdx.x; i < 1024; i += 256)
    sh[i] = quant1(a3f[b * 1024 + i], s3);
  __syncthreads();
  int ol = threadIdx.x >> 3, ks = threadIdx.x & 7;  // 32 oc x 8-way k-split
  int o = og * 32 + ol;
  const unsigned char* wp = ws8 + O_QFW1 + o * 1024 + ks * 128;
  const unsigned char* hp = sh + ks * 128;
  int acc = 0;
#pragma unroll 16
  for (int k = 0; k < 128; ++k)
    acc += ((int)hp[k] * (int)wp[k]) >> 8;
#pragma unroll
  for (int d = 4; d > 0; d >>= 1)
    acc += __shfl_down(acc, d, 8);
  float lm = 0.f;
  if (ks == 0) {
    float v = fmaxf(0.f, (float)acc + fb1[o]);
    a4[b * 256 + o] = v;
    lm = v;
  }
  lm = blk_max(lm, red);
  if (threadIdx.x == 0) atomicMax((unsigned int*)(wsf + 9), __float_as_uint(lm));
}

// ---- kernel 7: dense2 (256 -> 10) + log_softmax -> out (32,10)
__global__ __launch_bounds__(64) void k_dense2(const unsigned char* ws8, const float* a4,
                                               const float* fb2, float* out, const float* wsf) {
  int b = blockIdx.x;
  __shared__ unsigned char sh[256];
  __shared__ float z[10];
  float s4 = 255.0f / fmaxf(wsf[9], 1e-6f);
  for (int i = threadIdx.x; i < 256; i += 64)
    sh[i] = quant1(a4[b * 256 + i], s4);
  __syncthreads();
  if (threadIdx.x < 10) {
    const unsigned char* wp = ws8 + O_QFW2 + threadIdx.x * 256;
    int acc = 0;
#pragma unroll 8
    for (int k = 0; k < 256; ++k)
      acc += ((int)sh[k] * (int)wp[k]) >> 8;
    z[threadIdx.x] = (float)acc + fb2[threadIdx.x];
  }
  __syncthreads();
  if (threadIdx.x < 10) {
    float m = z[0];
#pragma unroll
    for (int j = 1; j < 10; ++j) m = fmaxf(m, z[j]);
    float se = 0.f;
#pragma unroll
    for (int j = 0; j < 10; ++j) se += expf(z[j] - m);
    out[b * 10 + threadIdx.x] = z[threadIdx.x] - (m + logf(se));
  }
}

extern "C" void kernel_launch(void* const* d_in, const int* in_sizes, int n_in,
                              void* d_out, int out_size, void* d_ws, size_t ws_size,
                              hipStream_t stream) {
  const float* x   = (const float*)d_in[0];
  // d_in[1] = lut, unused: lut[i][j] == (i*j)>>8 exactly, computed inline
  const float* w1  = (const float*)d_in[2];
  const float* b1  = (const float*)d_in[3];
  const float* w2  = (const float*)d_in[4];
  const float* b2  = (const float*)d_in[5];
  const float* w3  = (const float*)d_in[6];
  const float* b3  = (const float*)d_in[7];
  const float* fw1 = (const float*)d_in[8];
  const float* fb1 = (const float*)d_in[9];
  const float* fw2 = (const float*)d_in[10];
  const float* fb2 = (const float*)d_in[11];
  float* out = (float*)d_out;
  unsigned char* ws8 = (unsigned char*)d_ws;
  float* wsf = (float*)d_ws;
  float* A1 = (float*)(ws8 + O_A1);
  float* A2 = (float*)(ws8 + O_A2);
  float* A3 = (float*)(ws8 + O_A3);
  float* A4 = (float*)(ws8 + O_A4);

  k_maxes <<<6, 256, 0, stream>>>(x, w1, w2, w3, fw1, fw2, wsf);
  k_quant <<<dim3(1024, 6), 256, 0, stream>>>(x, w1, w2, w3, fw1, fw2, ws8, wsf);
  k_conv1 <<<dim3(32, 4), 256, 0, stream>>>(ws8, b1, A1, wsf);
  k_conv2 <<<dim3(32, 8), 256, 0, stream>>>(ws8, A1, b2, A2, wsf);
  k_conv3 <<<dim3(32, 8), 256, 0, stream>>>(ws8, A2, b3, A3, wsf);
  k_dense1<<<dim3(32, 8), 256, 0, stream>>>(ws8, A3, fb1, A4, wsf);
  k_dense2<<<32, 64, 0, stream>>>(ws8, A4, fb2, out, wsf);
}

// Round 2
// 212.041 us; speedup vs baseline: 1.7590x; 1.7590x over previous
//
#include <hip/hip_runtime.h>
#include <math.h>

// ---------------- workspace layout (bytes) ----------------
// [0..40)   : 10 float max slots: 0 x, 1 w1, 2 w2, 3 w3, 4 fw1, 5 fw2,
//             6 a1max, 7 a2max, 8 a3max, 9 a4max
#define O_QX    (1024)      // 25088 B  quantized x (32,1,28,28)
#define O_QW1   (32768)     // 400 B
#define O_QW2   (65536)     // 12800 B
#define O_QW3   (131072)    // 51200 B
#define O_QFW1  (262144)    // 262144 B
#define O_QFW2  (524288)    // 2560 B
#define O_A1    (589824)    // 100352 floats (32,16,14,14)
#define O_A2    (1048576)   // 50176 floats  (32,32,7,7)
#define O_A3    (1310720)   // 32768 floats  (32,1024)
#define O_A4    (1572864)   // 8192 floats   (32,256)

__device__ __forceinline__ float blk_max(float v, float* red) {
  int t = threadIdx.x;
  red[t] = v;
  __syncthreads();
  for (int s = (int)blockDim.x >> 1; s > 0; s >>= 1) {
    if (t < s) red[t] = fmaxf(red[t], red[t + s]);
    __syncthreads();
  }
  return red[0];
}

__device__ __forceinline__ unsigned char quant1(float v, float s) {
  float q = rintf(v * s);
  q = fminf(fmaxf(q, 0.0f), 255.0f);
  return (unsigned char)q;
}

// ---- kernel 0: zero the 10 max slots (ws is poisoned 0xAA; atomicMax needs 0 init)
__global__ __launch_bounds__(64) void k_init(float* wsf) {
  if (threadIdx.x < 10) wsf[threadIdx.x] = 0.f;
}

// ---- kernel 1: per-tensor abs-max of the 6 static tensors, parallel + vectorized.
// All quantized tensors here are non-negative after fabsf, so float-bits
// atomicMax on unsigned is order-correct.
__global__ __launch_bounds__(256) void k_maxes(const float* x, const float* w1, const float* w2,
                                               const float* w3, const float* fw1, const float* fw2,
                                               float* wsf) {
  __shared__ float red[256];
  const float* p; int n4;
  switch (blockIdx.y) {
    case 0: p = x;   n4 = 6272;  break;   // 25088/4
    case 1: p = w1;  n4 = 100;   break;
    case 2: p = w2;  n4 = 3200;  break;
    case 3: p = w3;  n4 = 12800; break;
    case 4: p = fw1; n4 = 65536; break;
    default: p = fw2; n4 = 640;  break;
  }
  const float4* p4 = (const float4*)p;
  float m = 0.f;
  for (int i = blockIdx.x * 256 + threadIdx.x; i < n4; i += gridDim.x * 256) {
    float4 v = p4[i];
    m = fmaxf(m, fmaxf(fmaxf(fabsf(v.x), fabsf(v.y)), fmaxf(fabsf(v.z), fabsf(v.w))));
  }
  m = blk_max(m, red);
  if (threadIdx.x == 0)
    atomicMax((unsigned int*)(wsf + blockIdx.y), __float_as_uint(m));
}

// ---- kernel 2: quantize x + all weights to uint8 in ws
__global__ __launch_bounds__(256) void k_quant(const float* x, const float* w1, const float* w2,
                                               const float* w3, const float* fw1, const float* fw2,
                                               unsigned char* ws8, const float* wsf) {
  const float* p; int n; unsigned char* d;
  switch (blockIdx.y) {
    case 0: p = x;   n = 25088;  d = ws8 + O_QX;   break;
    case 1: p = w1;  n = 400;    d = ws8 + O_QW1;  break;
    case 2: p = w2;  n = 12800;  d = ws8 + O_QW2;  break;
    case 3: p = w3;  n = 51200;  d = ws8 + O_QW3;  break;
    case 4: p = fw1; n = 262144; d = ws8 + O_QFW1; break;
    default: p = fw2; n = 2560;  d = ws8 + O_QFW2; break;
  }
  int i = blockIdx.x * 256 + threadIdx.x;
  if (i >= n) return;
  float s = 255.0f / fmaxf(wsf[blockIdx.y], 1e-6f);
  d[i] = quant1(p[i], s);
}

// ---- kernel 3: conv1 (1->16, 5x5 pad2) + relu + 2x2 maxpool -> A1 (32,16,14,14) + max slot 6
__global__ __launch_bounds__(256) void k_conv1(const unsigned char* ws8, const float* b1,
                                               float* a1, float* wsf) {
  int b = blockIdx.x, og = blockIdx.y;              // 4 out-channels per og (4 groups)
  __shared__ unsigned char sx[32 * 32];             // 28+4 padded
  __shared__ short sw[4 * 25];
  __shared__ float red[256];
  const unsigned char* qx = ws8 + O_QX + b * 784;
  const unsigned char* qw = ws8 + O_QW1 + og * 4 * 25;
  for (int i = threadIdx.x; i < 1024; i += 256) sx[i] = 0;
  __syncthreads();
  for (int i = threadIdx.x; i < 784; i += 256) {
    int y = i / 28, xx = i - y * 28;
    sx[(y + 2) * 32 + xx + 2] = qx[i];
  }
  for (int i = threadIdx.x; i < 100; i += 256) sw[i] = qw[i];
  __syncthreads();
  float lm = 0.f;
  for (int oi = threadIdx.x; oi < 784; oi += 256) {  // 4 oc * 196 pool px
    int ol = oi / 196, r = oi - ol * 196;
    int py = r / 14, px = r - py * 14;
    int o = og * 4 + ol;
    const short* w = sw + ol * 25;
    int best = -2147483647;
#pragma unroll
    for (int dy = 0; dy < 2; ++dy)
#pragma unroll
      for (int dx = 0; dx < 2; ++dx) {
        int cy = 2 * py + dy, cx = 2 * px + dx;
        int acc = 0;
#pragma unroll
        for (int kh = 0; kh < 5; ++kh) {
          const unsigned char* xp = sx + (cy + kh) * 32 + cx;
#pragma unroll
          for (int kw = 0; kw < 5; ++kw)
            acc += ((int)xp[kw] * (int)w[kh * 5 + kw]) >> 8;
        }
        best = max(best, acc);
      }
    float v = fmaxf(0.f, (float)best + b1[o]);
    a1[b * 3136 + o * 196 + r] = v;
    lm = fmaxf(lm, v);
  }
  lm = blk_max(lm, red);
  if (threadIdx.x == 0) atomicMax((unsigned int*)(wsf + 6), __float_as_uint(lm));
}

// ---- kernel 4: conv2 (16->32) + relu + pool -> A2 (32,32,7,7) + max slot 7
__global__ __launch_bounds__(256) void k_conv2(const unsigned char* ws8, const float* a1,
                                               const float* b2, float* a2, float* wsf) {
  int b = blockIdx.x, og = blockIdx.y;              // 4 oc per og (8 groups)
  __shared__ unsigned char sa[16 * 18 * 18];        // 14+4 padded per channel
  __shared__ short sw[4 * 400];
  __shared__ float red[256];
  float s1 = 255.0f / fmaxf(wsf[6], 1e-6f);
  for (int i = threadIdx.x; i < 16 * 324; i += 256) sa[i] = 0;
  __syncthreads();
  for (int i = threadIdx.x; i < 3136; i += 256) {
    int c = i / 196, r = i - c * 196;
    int y = r / 14, xx = r - y * 14;
    sa[c * 324 + (y + 2) * 18 + xx + 2] = quant1(a1[b * 3136 + i], s1);
  }
  const unsigned char* qw = ws8 + O_QW2 + og * 4 * 400;
  for (int i = threadIdx.x; i < 1600; i += 256) sw[i] = qw[i];
  __syncthreads();
  float lm = 0.f;
  int oi = threadIdx.x;
  if (oi < 196) {                                    // 4 oc * 49 pool px
    int ol = oi / 49, r = oi - ol * 49;
    int py = r / 7, px = r - py * 7;
    int o = og * 4 + ol;
    int best = -2147483647;
#pragma unroll
    for (int dy = 0; dy < 2; ++dy)
#pragma unroll
      for (int dx = 0; dx < 2; ++dx) {
        int cy = 2 * py + dy, cx = 2 * px + dx;      // 0..13
        int acc = 0;
        for (int c = 0; c < 16; ++c) {
          const unsigned char* ap = sa + c * 324 + cy * 18 + cx;
          const short* wp = sw + ol * 400 + c * 25;
#pragma unroll
          for (int kh = 0; kh < 5; ++kh)
#pragma unroll
            for (int kw = 0; kw < 5; ++kw)
              acc += ((int)ap[kh * 18 + kw] * (int)wp[kh * 5 + kw]) >> 8;
        }
        best = max(best, acc);
      }
    float v = fmaxf(0.f, (float)best + b2[o]);
    a2[b * 1568 + o * 49 + r] = v;
    lm = v;
  }
  lm = blk_max(lm, red);
  if (threadIdx.x == 0) atomicMax((unsigned int*)(wsf + 7), __float_as_uint(lm));
}

// ---- kernel 5: conv3 (32->64) + relu + pool(pad=1) -> A3 (32,1024) + max slot 8
__global__ __launch_bounds__(256) void k_conv3(const unsigned char* ws8, const float* a2,
                                               const float* b3, float* a3, float* wsf) {
  int b = blockIdx.x, og = blockIdx.y;              // 8 oc per og (8 groups)
  __shared__ unsigned char sa[32 * 11 * 11];        // 7+4 padded
  __shared__ short sw[8 * 800];
  __shared__ int part[256 * 4];
  __shared__ float red[256];
  float s2 = 255.0f / fmaxf(wsf[7], 1e-6f);
  for (int i = threadIdx.x; i < 32 * 121; i += 256) sa[i] = 0;
  __syncthreads();
  for (int i = threadIdx.x; i < 1568; i += 256) {
    int c = i / 49, r = i - c * 49;
    int y = r / 7, xx = r - y * 7;
    sa[c * 121 + (y + 2) * 11 + xx + 2] = quant1(a2[b * 1568 + i], s2);
  }
  const unsigned char* qw = ws8 + O_QW3 + og * 8 * 800;
  for (int i = threadIdx.x; i < 6400; i += 256) sw[i] = qw[i];
  __syncthreads();
  // 128 outputs (8 oc * 16 pool px), 2-way channel split
  int out  = threadIdx.x & 127;
  int half = threadIdx.x >> 7;
  int ol = out >> 4, r = out & 15;
  int py = r >> 2, px = r & 3;
#pragma unroll
  for (int dy = 0; dy < 2; ++dy)
#pragma unroll
    for (int dx = 0; dx < 2; ++dx) {
      int idx = dy * 2 + dx;
      int cy = 2 * py - 1 + dy, cx = 2 * px - 1 + dx;  // pool pad=1
      int acc;
      if (cy < 0 || cy > 6 || cx < 0 || cx > 6) {
        acc = -(1 << 28);
      } else {
        acc = 0;
        for (int ci = 0; ci < 16; ++ci) {
          int c = half * 16 + ci;
          const unsigned char* ap = sa + c * 121 + cy * 11 + cx;
          const short* wp = sw + ol * 800 + c * 25;
#pragma unroll
          for (int kh = 0; kh < 5; ++kh)
#pragma unroll
            for (int kw = 0; kw < 5; ++kw)
              acc += ((int)ap[kh * 11 + kw] * (int)wp[kh * 5 + kw]) >> 8;
        }
      }
      part[threadIdx.x * 4 + idx] = acc;
    }
  __syncthreads();
  float lm = 0.f;
  if (half == 0) {
    int best = -2147483647;
#pragma unroll
    for (int idx = 0; idx < 4; ++idx) {
      int acc = part[threadIdx.x * 4 + idx] + part[(threadIdx.x + 128) * 4 + idx];
      best = max(best, acc);
    }
    int o = og * 8 + ol;
    float v = fmaxf(0.f, (float)best + b3[o]);
    a3[b * 1024 + o * 16 + r] = v;   // flatten order (c, y, x)
    lm = v;
  }
  lm = blk_max(lm, red);
  if (threadIdx.x == 0) atomicMax((unsigned int*)(wsf + 8), __float_as_uint(lm));
}

// ---- kernel 6: dense1 (1024 -> 256) + relu -> A4 (32,256) + max slot 9
__global__ __launch_bounds__(256) void k_dense1(const unsigned char* ws8, const float* a3f,
                                                const float* fb1, float* a4, float* wsf) {
  int b = blockIdx.x, og = blockIdx.y;              // 32 oc per og (8 groups)
  __shared__ unsigned char sh[1024];
  __shared__ float red[256];
  float s3 = 255.0f / fmaxf(wsf[8], 1e-6f);
  for (int i = threadIdx.x; i < 1024; i += 256)
    sh[i] = quant1(a3f[b * 1024 + i], s3);
  __syncthreads();
  int ol = threadIdx.x >> 3, ks = threadIdx.x & 7;  // 32 oc x 8-way k-split
  int o = og * 32 + ol;
  const unsigned char* wp = ws8 + O_QFW1 + o * 1024 + ks * 128;
  const unsigned char* hp = sh + ks * 128;
  int acc = 0;
#pragma unroll 16
  for (int k = 0; k < 128; ++k)
    acc += ((int)hp[k] * (int)wp[k]) >> 8;
#pragma unroll
  for (int d = 4; d > 0; d >>= 1)
    acc += __shfl_down(acc, d, 8);
  float lm = 0.f;
  if (ks == 0) {
    float v = fmaxf(0.f, (float)acc + fb1[o]);
    a4[b * 256 + o] = v;
    lm = v;
  }
  lm = blk_max(lm, red);
  if (threadIdx.x == 0) atomicMax((unsigned int*)(wsf + 9), __float_as_uint(lm));
}

// ---- kernel 7: dense2 (256 -> 10) + log_softmax -> out (32,10)
__global__ __launch_bounds__(64) void k_dense2(const unsigned char* ws8, const float* a4,
                                               const float* fb2, float* out, const float* wsf) {
  int b = blockIdx.x;
  __shared__ unsigned char sh[256];
  __shared__ float z[10];
  float s4 = 255.0f / fmaxf(wsf[9], 1e-6f);
  for (int i = threadIdx.x; i < 256; i += 64)
    sh[i] = quant1(a4[b * 256 + i], s4);
  __syncthreads();
  if (threadIdx.x < 10) {
    const unsigned char* wp = ws8 + O_QFW2 + threadIdx.x * 256;
    int acc = 0;
#pragma unroll 8
    for (int k = 0; k < 256; ++k)
      acc += ((int)sh[k] * (int)wp[k]) >> 8;
    z[threadIdx.x] = (float)acc + fb2[threadIdx.x];
  }
  __syncthreads();
  if (threadIdx.x < 10) {
    float m = z[0];
#pragma unroll
    for (int j = 1; j < 10; ++j) m = fmaxf(m, z[j]);
    float se = 0.f;
#pragma unroll
    for (int j = 0; j < 10; ++j) se += expf(z[j] - m);
    out[b * 10 + threadIdx.x] = z[threadIdx.x] - (m + logf(se));
  }
}

extern "C" void kernel_launch(void* const* d_in, const int* in_sizes, int n_in,
                              void* d_out, int out_size, void* d_ws, size_t ws_size,
                              hipStream_t stream) {
  const float* x   = (const float*)d_in[0];
  // d_in[1] = lut, unused: lut[i][j] == (i*j)>>8 exactly, computed inline
  const float* w1  = (const float*)d_in[2];
  const float* b1  = (const float*)d_in[3];
  const float* w2  = (const float*)d_in[4];
  const float* b2  = (const float*)d_in[5];
  const float* w3  = (const float*)d_in[6];
  const float* b3  = (const float*)d_in[7];
  const float* fw1 = (const float*)d_in[8];
  const float* fb1 = (const float*)d_in[9];
  const float* fw2 = (const float*)d_in[10];
  const float* fb2 = (const float*)d_in[11];
  float* out = (float*)d_out;
  unsigned char* ws8 = (unsigned char*)d_ws;
  float* wsf = (float*)d_ws;
  float* A1 = (float*)(ws8 + O_A1);
  float* A2 = (float*)(ws8 + O_A2);
  float* A3 = (float*)(ws8 + O_A3);
  float* A4 = (float*)(ws8 + O_A4);

  k_init  <<<1, 64, 0, stream>>>(wsf);
  k_maxes <<<dim3(32, 6), 256, 0, stream>>>(x, w1, w2, w3, fw1, fw2, wsf);
  k_quant <<<dim3(1024, 6), 256, 0, stream>>>(x, w1, w2, w3, fw1, fw2, ws8, wsf);
  k_conv1 <<<dim3(32, 4), 256, 0, stream>>>(ws8, b1, A1, wsf);
  k_conv2 <<<dim3(32, 8), 256, 0, stream>>>(ws8, A1, b2, A2, wsf);
  k_conv3 <<<dim3(32, 8), 256, 0, stream>>>(ws8, A2, b3, A3, wsf);
  k_dense1<<<dim3(32, 8), 256, 0, stream>>>(ws8, A3, fb1, A4, wsf);
  k_dense2<<<32, 64, 0, stream>>>(ws8, A4, fb2, out, wsf);
}

// Round 3
// 148.293 us; speedup vs baseline: 2.5152x; 1.4299x over previous
//
#include <hip/hip_runtime.h>
#include <math.h>

typedef unsigned int  u32;
typedef unsigned short u16;
typedef unsigned short u16x2 __attribute__((ext_vector_type(2)));

// ---------------- workspace layout (bytes) ----------------
// [0..40): 10 float max slots: 0 x, 1 w1, 2 w2, 3 w3, 4 fw1, 5 fw2,
//          6 a1max, 7 a2max, 8 a3max, 9 a4max
#define O_QX    1024      // u8  [32][784]
#define O_QW1   26624     // u16 [16][25]
#define O_QW2   28672     // u16 [32][25][16]   (tap-major, channel-last)
#define O_QW3   57344     // u16 [64][25][32]
#define O_QFW1  163840    // u16 [256][1024]
#define O_QFW2  690176    // u16 [10][256]
#define O_A1    696320    // f32 [32][16][196]
#define O_A2    1098752   // f32 [32][32][49]
#define O_A3    1300480   // f32 [32][1024]
#define O_A4    1432576   // f32 [32][256]

__device__ __forceinline__ float blk_max(float v, float* red) {
  int t = threadIdx.x;
  red[t] = v;
  __syncthreads();
  for (int s = (int)blockDim.x >> 1; s > 0; s >>= 1) {
    if (t < s) red[t] = fmaxf(red[t], red[t + s]);
    __syncthreads();
  }
  return red[0];
}

__device__ __forceinline__ u16 quant1(float v, float s) {
  float q = rintf(v * s);
  q = fminf(fmaxf(q, 0.0f), 255.0f);
  return (u16)q;
}

// packed 2-MAC: acc += floor(a0*w0/256) + floor(a1*w1/256) in packed halves.
// products <= 255*255 = 65025 fit u16 exactly; each half accumulates <= 254/add.
__device__ __forceinline__ void mac_u32(u32& acc, u32 a, u32 w) {
  u16x2 av = __builtin_bit_cast(u16x2, a);
  u16x2 wv = __builtin_bit_cast(u16x2, w);
  u16x2 p  = av * wv;                    // v_pk_mul_lo_u16, exact
  acc += (__builtin_bit_cast(u32, p) >> 8) & 0x00FF00FFu;
}
__device__ __forceinline__ void mac4(u32& acc, uint4 a, uint4 w) {
  mac_u32(acc, a.x, w.x); mac_u32(acc, a.y, w.y);
  mac_u32(acc, a.z, w.z); mac_u32(acc, a.w, w.w);
}

// ---- kernel 0: zero the 10 max slots (ws poisoned 0xAA; atomicMax needs 0)
__global__ __launch_bounds__(64) void k_init(float* wsf) {
  if (threadIdx.x < 10) wsf[threadIdx.x] = 0.f;
}

// ---- kernel 1: per-tensor abs-max of the 6 static tensors
__global__ __launch_bounds__(256) void k_maxes(const float* x, const float* w1, const float* w2,
                                               const float* w3, const float* fw1, const float* fw2,
                                               float* wsf) {
  __shared__ float red[256];
  const float* p; int n4;
  switch (blockIdx.y) {
    case 0: p = x;   n4 = 6272;  break;
    case 1: p = w1;  n4 = 100;   break;
    case 2: p = w2;  n4 = 3200;  break;
    case 3: p = w3;  n4 = 12800; break;
    case 4: p = fw1; n4 = 65536; break;
    default: p = fw2; n4 = 640;  break;
  }
  const float4* p4 = (const float4*)p;
  float m = 0.f;
  for (int i = blockIdx.x * 256 + threadIdx.x; i < n4; i += gridDim.x * 256) {
    float4 v = p4[i];
    m = fmaxf(m, fmaxf(fmaxf(fabsf(v.x), fabsf(v.y)), fmaxf(fabsf(v.z), fabsf(v.w))));
  }
  m = blk_max(m, red);
  if (threadIdx.x == 0)
    atomicMax((u32*)(wsf + blockIdx.y), __float_as_uint(m));
}

// ---- kernel 2: quantize x (u8) + all weights (u16, conv weights tap-major/channel-last)
__global__ __launch_bounds__(256) void k_quant(const float* x, const float* w1, const float* w2,
                                               const float* w3, const float* fw1, const float* fw2,
                                               unsigned char* ws8, const float* wsf) {
  int y = blockIdx.y;
  float s = 255.0f / fmaxf(wsf[y], 1e-6f);
  const float* p; int n;
  switch (y) {
    case 0: p = x;   n = 25088;  break;
    case 1: p = w1;  n = 400;    break;
    case 2: p = w2;  n = 12800;  break;
    case 3: p = w3;  n = 51200;  break;
    case 4: p = fw1; n = 262144; break;
    default: p = fw2; n = 2560;  break;
  }
  for (int i = blockIdx.x * 256 + threadIdx.x; i < n; i += gridDim.x * 256) {
    u16 q = quant1(p[i], s);
    switch (y) {
      case 0: ws8[O_QX + i] = (unsigned char)q; break;
      case 1: ((u16*)(ws8 + O_QW1))[i] = q; break;
      case 2: { int o = i / 400, r = i - o * 400, c = r / 25, tp = r - c * 25;
                ((u16*)(ws8 + O_QW2))[o * 400 + tp * 16 + c] = q; } break;
      case 3: { int o = i / 800, r = i - o * 800, c = r / 25, tp = r - c * 25;
                ((u16*)(ws8 + O_QW3))[o * 800 + tp * 32 + c] = q; } break;
      case 4: ((u16*)(ws8 + O_QFW1))[i] = q; break;
      default: ((u16*)(ws8 + O_QFW2))[i] = q; break;
    }
  }
}

// ---- kernel 3: conv1 (1->16) + relu + pool -> A1 [32][16][196], max slot 6
__global__ __launch_bounds__(256) void k_conv1(const unsigned char* ws8, const float* b1,
                                               float* a1, float* wsf) {
  int b = blockIdx.x, oc = blockIdx.y;
  __shared__ unsigned char sx[32 * 32];
  __shared__ u16 sw[32];
  __shared__ float red[256];
  const unsigned char* qx = ws8 + O_QX + b * 784;
  const u16* qw = (const u16*)(ws8 + O_QW1) + oc * 25;
  for (int i = threadIdx.x; i < 1024; i += 256) sx[i] = 0;
  __syncthreads();
  for (int i = threadIdx.x; i < 784; i += 256) {
    int y = i / 28, xx = i - y * 28;
    sx[(y + 2) * 32 + xx + 2] = qx[i];
  }
  if (threadIdx.x < 25) sw[threadIdx.x] = qw[threadIdx.x];
  __syncthreads();
  float lm = 0.f;
  int t = threadIdx.x;
  if (t < 196) {
    int py = t / 14, px = t - py * 14;
    int best = -2147483647;
#pragma unroll
    for (int dy = 0; dy < 2; ++dy)
#pragma unroll
      for (int dx = 0; dx < 2; ++dx) {
        int cy = 2 * py + dy, cx = 2 * px + dx;
        int acc = 0;
#pragma unroll
        for (int kh = 0; kh < 5; ++kh) {
          const unsigned char* xp = sx + (cy + kh) * 32 + cx;
#pragma unroll
          for (int kw = 0; kw < 5; ++kw)
            acc += ((int)xp[kw] * (int)sw[kh * 5 + kw]) >> 8;
        }
        best = max(best, acc);
      }
    float v = fmaxf(0.f, (float)best + b1[oc]);
    a1[b * 3136 + oc * 196 + t] = v;
    lm = v;
  }
  lm = blk_max(lm, red);
  if (t == 0) atomicMax((u32*)(wsf + 6), __float_as_uint(lm));
}

// ---- kernel 4: conv2 (16->32), 1 oc/block, 1 thread/conv px, packed u16 math
__global__ __launch_bounds__(256) void k_conv2(const unsigned char* ws8, const float* a1,
                                               const float* b2, float* a2, float* wsf) {
  int b = blockIdx.x, oc = blockIdx.y;
  __shared__ __align__(16) u16 sa[324 * 16];  // [18*18 px][16 ch] zero-padded
  __shared__ int sconv[196];
  __shared__ float red[256];
  float s1 = 255.0f / fmaxf(wsf[6], 1e-6f);
  u32* sz = (u32*)sa;
  for (int i = threadIdx.x; i < 2592; i += 256) sz[i] = 0;
  __syncthreads();
  for (int i = threadIdx.x; i < 3136; i += 256) {
    int c = i / 196, r = i - c * 196;
    int y = r / 14, xx = r - y * 14;
    sa[((y + 2) * 18 + xx + 2) * 16 + c] = quant1(a1[b * 3136 + i], s1);
  }
  __syncthreads();
  int t = threadIdx.x;
  if (t < 196) {
    int y = t / 14, xx = t - y * 14;
    const uint4* wrow = (const uint4*)(ws8 + O_QW2 + oc * 800);  // wave-uniform
    u32 acc = 0;                    // 200 packed adds * 254 < 2^16: exact
#pragma unroll
    for (int kh = 0; kh < 5; ++kh)
#pragma unroll
      for (int kw = 0; kw < 5; ++kw) {
        const uint4* ap = (const uint4*)(sa + ((y + kh) * 18 + xx + kw) * 16);
        int tap = kh * 5 + kw;
        mac4(acc, ap[0], wrow[tap * 2]);
        mac4(acc, ap[1], wrow[tap * 2 + 1]);
      }
    sconv[t] = (int)((acc & 0xFFFFu) + (acc >> 16));
  }
  __syncthreads();
  float lm = 0.f;
  if (t < 49) {
    int py = t / 7, px = t - py * 7;
    int m = sconv[(2 * py) * 14 + 2 * px];
    m = max(m, sconv[(2 * py) * 14 + 2 * px + 1]);
    m = max(m, sconv[(2 * py + 1) * 14 + 2 * px]);
    m = max(m, sconv[(2 * py + 1) * 14 + 2 * px + 1]);
    float v = fmaxf(0.f, (float)m + b2[oc]);
    a2[b * 1568 + oc * 49 + t] = v;
    lm = v;
  }
  lm = blk_max(lm, red);
  if (t == 0) atomicMax((u32*)(wsf + 7), __float_as_uint(lm));
}

// ---- kernel 5: conv3 (32->64), 4 oc/block, thread=(oc, pool px, dydx), pool pad=1
__global__ __launch_bounds__(256) void k_conv3(const unsigned char* ws8, const float* a2,
                                               const float* b3, float* a3, float* wsf) {
  int b = blockIdx.x, og = blockIdx.y;
  __shared__ __align__(16) u16 sa[121 * 32];  // [11*11 px][32 ch] zero-padded
  __shared__ int spart[256];
  __shared__ float red[256];
  float s2 = 255.0f / fmaxf(wsf[7], 1e-6f);
  u32* sz = (u32*)sa;
  for (int i = threadIdx.x; i < 1936; i += 256) sz[i] = 0;
  __syncthreads();
  for (int i = threadIdx.x; i < 1568; i += 256) {
    int c = i / 49, r = i - c * 49;
    int y = r / 7, xx = r - y * 7;
    sa[((y + 2) * 11 + xx + 2) * 32 + c] = quant1(a2[b * 1568 + i], s2);
  }
  __syncthreads();
  int t = threadIdx.x;
  int ol = t >> 6, s = t & 63;         // ol uniform per wave -> scalar weight loads
  int r = s >> 2, dydx = s & 3;
  int py = r >> 2, px = r & 3;
  int cy = 2 * py - 1 + (dydx >> 1), cx = 2 * px - 1 + (dydx & 1);
  int oc = og * 4 + ol;
  int val = -(1 << 30);
  if (cy >= 0 && cy < 7 && cx >= 0 && cx < 7) {
    const uint4* wrow = (const uint4*)(ws8 + O_QW3 + oc * 1600);
    u32 acc0 = 0, acc1 = 0;          // 2 accs: 200 adds each, exact
#pragma unroll
    for (int kh = 0; kh < 5; ++kh)
#pragma unroll
      for (int kw = 0; kw < 5; ++kw) {
        const uint4* ap = (const uint4*)(sa + ((cy + kh) * 11 + cx + kw) * 32);
        int tap = kh * 5 + kw;
        mac4(acc0, ap[0], wrow[tap * 4]);
        mac4(acc0, ap[1], wrow[tap * 4 + 1]);
        mac4(acc1, ap[2], wrow[tap * 4 + 2]);
        mac4(acc1, ap[3], wrow[tap * 4 + 3]);
      }
    val = (int)((acc0 & 0xFFFFu) + (acc0 >> 16) + (acc1 & 0xFFFFu) + (acc1 >> 16));
  }
  spart[t] = val;
  __syncthreads();
  float lm = 0.f;
  if (t < 64) {
    int ol2 = t >> 4, r2 = t & 15;
    int base = ol2 * 64 + r2 * 4;
    int m = max(max(spart[base], spart[base + 1]), max(spart[base + 2], spart[base + 3]));
    int oc2 = og * 4 + ol2;
    float v = fmaxf(0.f, (float)m + b3[oc2]);
    a3[b * 1024 + oc2 * 16 + r2] = v;
    lm = v;
  }
  lm = blk_max(lm, red);
  if (t == 0) atomicMax((u32*)(wsf + 8), __float_as_uint(lm));
}

// ---- kernel 6: dense1 (1024->256) + relu -> A4, max slot 9
__global__ __launch_bounds__(256) void k_dense1(const unsigned char* ws8, const float* a3f,
                                                const float* fb1, float* a4, float* wsf) {
  int b = blockIdx.x, og = blockIdx.y;
  __shared__ __align__(16) u16 sh[1024];
  __shared__ float red[256];
  float s3 = 255.0f / fmaxf(wsf[8], 1e-6f);
  for (int i = threadIdx.x; i < 1024; i += 256)
    sh[i] = quant1(a3f[b * 1024 + i], s3);
  __syncthreads();
  int t = threadIdx.x;
  int ol = t >> 3, ks = t & 7;
  int o = og * 32 + ol;
  const uint4* wp = (const uint4*)(ws8 + O_QFW1 + o * 2048 + ks * 256);
  const uint4* hp = (const uint4*)(sh + ks * 128);
  u32 acc = 0;                        // 64 packed adds: exact
#pragma unroll
  for (int j = 0; j < 16; ++j)
    mac4(acc, hp[j], wp[j]);
  int ai = (int)((acc & 0xFFFFu) + (acc >> 16));
#pragma unroll
  for (int d = 4; d > 0; d >>= 1)
    ai += __shfl_down(ai, d, 8);
  float lm = 0.f;
  if (ks == 0) {
    float v = fmaxf(0.f, (float)ai + fb1[o]);
    a4[b * 256 + o] = v;
    lm = v;
  }
  lm = blk_max(lm, red);
  if (t == 0) atomicMax((u32*)(wsf + 9), __float_as_uint(lm));
}

// ---- kernel 7: dense2 (256->10) + log_softmax -> out (32,10)
__global__ __launch_bounds__(64) void k_dense2(const unsigned char* ws8, const float* a4,
                                               const float* fb2, float* out, const float* wsf) {
  int b = blockIdx.x;
  __shared__ __align__(16) u16 sh[256];
  __shared__ float z[16];
  float s4 = 255.0f / fmaxf(wsf[9], 1e-6f);
  for (int i = threadIdx.x; i < 256; i += 64)
    sh[i] = quant1(a4[b * 256 + i], s4);
  __syncthreads();
  int t = threadIdx.x;
  int o = t >> 2, ks = t & 3;
  if (t < 40) {
    const uint4* wp = (const uint4*)(ws8 + O_QFW2 + o * 512 + ks * 128);
    const uint4* hp = (const uint4*)(sh + ks * 64);
    u32 acc = 0;
#pragma unroll
    for (int j = 0; j < 8; ++j)
      mac4(acc, hp[j], wp[j]);
    int ai = (int)((acc & 0xFFFFu) + (acc >> 16));
    ai += __shfl_down(ai, 2, 4);
    ai += __shfl_down(ai, 1, 4);
    if (ks == 0) z[o] = (float)ai + fb2[o];
  }
  __syncthreads();
  if (t < 10) {
    float m = z[0];
#pragma unroll
    for (int j = 1; j < 10; ++j) m = fmaxf(m, z[j]);
    float se = 0.f;
#pragma unroll
    for (int j = 0; j < 10; ++j) se += expf(z[j] - m);
    out[b * 10 + t] = z[t] - (m + logf(se));
  }
}

extern "C" void kernel_launch(void* const* d_in, const int* in_sizes, int n_in,
                              void* d_out, int out_size, void* d_ws, size_t ws_size,
                              hipStream_t stream) {
  const float* x   = (const float*)d_in[0];
  // d_in[1] = lut, unused: lut[i][j] == (i*j)>>8 exactly, computed inline
  const float* w1  = (const float*)d_in[2];
  const float* b1  = (const float*)d_in[3];
  const float* w2  = (const float*)d_in[4];
  const float* b2  = (const float*)d_in[5];
  const float* w3  = (const float*)d_in[6];
  const float* b3  = (const float*)d_in[7];
  const float* fw1 = (const float*)d_in[8];
  const float* fb1 = (const float*)d_in[9];
  const float* fw2 = (const float*)d_in[10];
  const float* fb2 = (const float*)d_in[11];
  float* out = (float*)d_out;
  unsigned char* ws8 = (unsigned char*)d_ws;
  float* wsf = (float*)d_ws;
  float* A1 = (float*)(ws8 + O_A1);
  float* A2 = (float*)(ws8 + O_A2);
  float* A3 = (float*)(ws8 + O_A3);
  float* A4 = (float*)(ws8 + O_A4);

  k_init  <<<1, 64, 0, stream>>>(wsf);
  k_maxes <<<dim3(32, 6), 256, 0, stream>>>(x, w1, w2, w3, fw1, fw2, wsf);
  k_quant <<<dim3(128, 6), 256, 0, stream>>>(x, w1, w2, w3, fw1, fw2, ws8, wsf);
  k_conv1 <<<dim3(32, 16), 256, 0, stream>>>(ws8, b1, A1, wsf);
  k_conv2 <<<dim3(32, 32), 256, 0, stream>>>(ws8, A1, b2, A2, wsf);
  k_conv3 <<<dim3(32, 16), 256, 0, stream>>>(ws8, A2, b3, A3, wsf);
  k_dense1<<<dim3(32, 8), 256, 0, stream>>>(ws8, A3, fb1, A4, wsf);
  k_dense2<<<32, 64, 0, stream>>>(ws8, A4, fb2, out, wsf);
}